// Round 1
// baseline (1263.310 us; speedup 1.0000x reference)
//
#include <hip/hip_runtime.h>
#include <cstddef>
#include <cstdint>

#define B_   2
#define S_   2048
#define HID  1024
#define NH_  16
#define NKV_ 4
#define DH_  64
#define ROWS (B_ * S_)   // 4096

// ---------------------------------------------------------------------------
// GEMM: C[M,N] = A[M,K] @ W[K,N] + bias[N]   (fp32, 128x128 tile, 8x8 micro)
// M,N multiples of 128; K multiple of 16. 256 threads.
// ---------------------------------------------------------------------------
__global__ __launch_bounds__(256) void gemm_bias_128(
    const float* __restrict__ A, const float* __restrict__ W,
    const float* __restrict__ bias, float* __restrict__ C,
    int M, int N, int K)
{
  __shared__ float As[16][128];   // [k][m] (transposed A tile)
  __shared__ float Bs[16][128];   // [k][n]
  const int tid = threadIdx.x;
  const int bm = blockIdx.y * 128;
  const int bn = blockIdx.x * 128;
  const int ar  = tid >> 1;          // 0..127 : A tile row
  const int ak  = (tid & 1) * 8;     // 0 or 8 : A tile k-offset
  const int bkr = tid >> 4;          // 0..15  : B tile k-row
  const int bc  = (tid & 15) * 8;    // 0..120 : B tile col
  const int mb  = (tid >> 4) * 8;    // micro-tile row base
  const int nb  = (tid & 15) * 8;    // micro-tile col base

  float acc[8][8];
#pragma unroll
  for (int i = 0; i < 8; ++i)
#pragma unroll
    for (int j = 0; j < 8; ++j) acc[i][j] = 0.f;

  const float* Ap = A + (size_t)(bm + ar) * K + ak;
  const float* Wp = W + (size_t)bkr * N + (bn + bc);

  for (int k0 = 0; k0 < K; k0 += 16) {
    float4 a0 = *(const float4*)(Ap + k0);
    float4 a1 = *(const float4*)(Ap + k0 + 4);
    float4 b0 = *(const float4*)(Wp + (size_t)k0 * N);
    float4 b1 = *(const float4*)(Wp + (size_t)k0 * N + 4);
    __syncthreads();   // previous iter's compute reads done before overwrite
    As[ak+0][ar] = a0.x; As[ak+1][ar] = a0.y; As[ak+2][ar] = a0.z; As[ak+3][ar] = a0.w;
    As[ak+4][ar] = a1.x; As[ak+5][ar] = a1.y; As[ak+6][ar] = a1.z; As[ak+7][ar] = a1.w;
    *(float4*)&Bs[bkr][bc]   = b0;
    *(float4*)&Bs[bkr][bc+4] = b1;
    __syncthreads();
#pragma unroll
    for (int kk = 0; kk < 16; ++kk) {
      float av[8], bv[8];
      *(float4*)&av[0] = *(const float4*)&As[kk][mb];
      *(float4*)&av[4] = *(const float4*)&As[kk][mb+4];
      *(float4*)&bv[0] = *(const float4*)&Bs[kk][nb];
      *(float4*)&bv[4] = *(const float4*)&Bs[kk][nb+4];
#pragma unroll
      for (int i = 0; i < 8; ++i)
#pragma unroll
        for (int j = 0; j < 8; ++j)
          acc[i][j] = fmaf(av[i], bv[j], acc[i][j]);
    }
  }

  float bvv[8];
#pragma unroll
  for (int j = 0; j < 8; ++j) bvv[j] = bias[bn + nb + j];
#pragma unroll
  for (int i = 0; i < 8; ++i) {
    float4 r0, r1;
    r0.x = acc[i][0] + bvv[0]; r0.y = acc[i][1] + bvv[1];
    r0.z = acc[i][2] + bvv[2]; r0.w = acc[i][3] + bvv[3];
    r1.x = acc[i][4] + bvv[4]; r1.y = acc[i][5] + bvv[5];
    r1.z = acc[i][6] + bvv[6]; r1.w = acc[i][7] + bvv[7];
    float* cp = C + (size_t)(bm + mb + i) * N + (bn + nb);
    *(float4*)cp       = r0;
    *(float4*)(cp + 4) = r1;
  }
}

// ---------------------------------------------------------------------------
// RoPE (in-place), replicating the reference exactly:
//   angle(d) = s * theta^(-(d mod 32)/32)      [concat cos/sin layout]
//   rotate pairs are interleaved: y[2i]   = x[2i]*cos(a(2i))   - x[2i+1]*sin(a(2i))
//                                 y[2i+1] = x[2i+1]*cos(a(2i+1)) + x[2i]*sin(a(2i+1))
// buf is [ROWS, ncols]; seq position = row % S_.
// ---------------------------------------------------------------------------
__global__ void rope_kernel(float* __restrict__ buf, int ncols, int total_pairs)
{
  int idx = blockIdx.x * blockDim.x + threadIdx.x;
  if (idx >= total_pairs) return;
  const int npr = ncols >> 1;              // pairs per row
  const int row = idx / npr;
  const int p   = idx - row * npr;
  const int col0 = p * 2;
  const int d0 = col0 & (DH_ - 1);         // within-head dim (even)
  const int s  = row & (S_ - 1);
  const float L = 0.51905126482615037f;    // log2(100000)/32
  const float sf = (float)s;
  float ang0 = sf * exp2f(-L * (float)(d0 & 31));
  float ang1 = sf * exp2f(-L * (float)((d0 + 1) & 31));
  float* ptr = buf + (size_t)row * ncols + col0;
  float x0 = ptr[0], x1 = ptr[1];
  ptr[0] = x0 * cosf(ang0) - x1 * sinf(ang0);
  ptr[1] = x1 * cosf(ang1) + x0 * sinf(ang1);
}

// ---------------------------------------------------------------------------
// Flash-style causal GQA attention.
// Q: [ROWS, NH_*DH_] (pre-RoPE'd), K/V: [ROWS, NKV_*DH_], mask: [B_,S_].
// Block = 256 threads handles one (b, h, 32 q-rows); iterates 64-wide k-tiles.
// Each thread owns row ro = tid/8, cols co = (tid%8)*8 of scores/P/O.
// Online softmax state (m,l) replicated across each 8-lane row group.
// ---------------------------------------------------------------------------
__global__ __launch_bounds__(256) void attn_kernel(
    const float* __restrict__ Q, const float* __restrict__ K,
    const float* __restrict__ V, const int* __restrict__ amask,
    float* __restrict__ Oout)
{
  __shared__ float Qs[32][65];    // padded: kills 8-way bank conflict on broadcast
  __shared__ float Kst[64][64];   // [d][k] transposed
  __shared__ float Vs[64][64];    // [k][d]
  __shared__ float Ps[32][65];    // padded
  __shared__ int   Msk[64];

  const int tid = threadIdx.x;
  const int q0  = blockIdx.x * 32;
  const int h   = blockIdx.y;
  const int b   = blockIdx.z;
  const int kvh = h >> 2;         // GQA: repeat(k,4,axis=2) -> head h uses kv h/4

  // load Q tile, pre-scaled by 1/sqrt(64)
  {
    const int r = tid >> 3;
    const int c = (tid & 7) * 8;
    const float* src = Q + (size_t)(b * S_ + q0 + r) * HID + h * DH_ + c;
    float4 v0 = *(const float4*)src;
    float4 v1 = *(const float4*)(src + 4);
    Qs[r][c+0] = v0.x * 0.125f; Qs[r][c+1] = v0.y * 0.125f;
    Qs[r][c+2] = v0.z * 0.125f; Qs[r][c+3] = v0.w * 0.125f;
    Qs[r][c+4] = v1.x * 0.125f; Qs[r][c+5] = v1.y * 0.125f;
    Qs[r][c+6] = v1.z * 0.125f; Qs[r][c+7] = v1.w * 0.125f;
  }

  const int ro = tid >> 3;         // owned q-row (0..31)
  const int co = (tid & 7) * 8;    // owned col base (0..56)
  float Oacc[8] = {0.f,0.f,0.f,0.f,0.f,0.f,0.f,0.f};
  float m_i = -1e30f, l_i = 0.f;

  const int nkt = ((q0 + 31) >> 6) + 1;   // causal: only tiles with k <= q0+31
  for (int kt = 0; kt < nkt; ++kt) {
    const int kbase = kt * 64;
    __syncthreads();   // prev iter's PV reads of Vs/Ps done
    {
      const int kr = tid >> 2;
      const int c  = (tid & 3) * 16;
      const size_t roff = (size_t)(b * S_ + kbase + kr) * (NKV_ * DH_) + kvh * DH_ + c;
      const float4 k0 = *(const float4*)(K + roff);
      const float4 k1 = *(const float4*)(K + roff + 4);
      const float4 k2 = *(const float4*)(K + roff + 8);
      const float4 k3 = *(const float4*)(K + roff + 12);
      Kst[c+0][kr]=k0.x; Kst[c+1][kr]=k0.y; Kst[c+2][kr]=k0.z; Kst[c+3][kr]=k0.w;
      Kst[c+4][kr]=k1.x; Kst[c+5][kr]=k1.y; Kst[c+6][kr]=k1.z; Kst[c+7][kr]=k1.w;
      Kst[c+8][kr]=k2.x; Kst[c+9][kr]=k2.y; Kst[c+10][kr]=k2.z; Kst[c+11][kr]=k2.w;
      Kst[c+12][kr]=k3.x; Kst[c+13][kr]=k3.y; Kst[c+14][kr]=k3.z; Kst[c+15][kr]=k3.w;
      const float4 v0 = *(const float4*)(V + roff);
      const float4 v1 = *(const float4*)(V + roff + 4);
      const float4 v2 = *(const float4*)(V + roff + 8);
      const float4 v3 = *(const float4*)(V + roff + 12);
      *(float4*)&Vs[kr][c]    = v0;
      *(float4*)&Vs[kr][c+4]  = v1;
      *(float4*)&Vs[kr][c+8]  = v2;
      *(float4*)&Vs[kr][c+12] = v3;
      if (tid < 64) Msk[tid] = amask[b * S_ + kbase + tid];
    }
    __syncthreads();

    // scores for (ro, co..co+7)
    float s[8] = {0.f,0.f,0.f,0.f,0.f,0.f,0.f,0.f};
#pragma unroll
    for (int d = 0; d < 64; ++d) {
      const float qv = Qs[ro][d];
      const float4 ka = *(const float4*)&Kst[d][co];
      const float4 kb = *(const float4*)&Kst[d][co+4];
      s[0] = fmaf(qv, ka.x, s[0]); s[1] = fmaf(qv, ka.y, s[1]);
      s[2] = fmaf(qv, ka.z, s[2]); s[3] = fmaf(qv, ka.w, s[3]);
      s[4] = fmaf(qv, kb.x, s[4]); s[5] = fmaf(qv, kb.y, s[5]);
      s[6] = fmaf(qv, kb.z, s[6]); s[7] = fmaf(qv, kb.w, s[7]);
    }
    const int qg = q0 + ro;
#pragma unroll
    for (int j = 0; j < 8; ++j) {
      const int kg = kbase + co + j;
      if (kg > qg || Msk[co + j] == 0) s[j] = -1e30f;
    }

    // online softmax (8-lane row group)
    float mx = s[0];
#pragma unroll
    for (int j = 1; j < 8; ++j) mx = fmaxf(mx, s[j]);
    mx = fmaxf(mx, __shfl_xor(mx, 1));
    mx = fmaxf(mx, __shfl_xor(mx, 2));
    mx = fmaxf(mx, __shfl_xor(mx, 4));
    const float m_new = fmaxf(m_i, mx);
    const float alpha = __expf(m_i - m_new);
    float p[8], ssum = 0.f;
#pragma unroll
    for (int j = 0; j < 8; ++j) { p[j] = __expf(s[j] - m_new); ssum += p[j]; }
    ssum += __shfl_xor(ssum, 1);
    ssum += __shfl_xor(ssum, 2);
    ssum += __shfl_xor(ssum, 4);
    l_i = l_i * alpha + ssum;
    m_i = m_new;
#pragma unroll
    for (int j = 0; j < 8; ++j) Oacc[j] *= alpha;
#pragma unroll
    for (int j = 0; j < 8; ++j) Ps[ro][co + j] = p[j];
    __syncthreads();

    // PV: O[ro][co..] += P[ro][k] * V[k][co..]
#pragma unroll
    for (int k = 0; k < 64; ++k) {
      const float pk = Ps[ro][k];
      const float4 va = *(const float4*)&Vs[k][co];
      const float4 vb = *(const float4*)&Vs[k][co+4];
      Oacc[0] = fmaf(pk, va.x, Oacc[0]); Oacc[1] = fmaf(pk, va.y, Oacc[1]);
      Oacc[2] = fmaf(pk, va.z, Oacc[2]); Oacc[3] = fmaf(pk, va.w, Oacc[3]);
      Oacc[4] = fmaf(pk, vb.x, Oacc[4]); Oacc[5] = fmaf(pk, vb.y, Oacc[5]);
      Oacc[6] = fmaf(pk, vb.z, Oacc[6]); Oacc[7] = fmaf(pk, vb.w, Oacc[7]);
    }
  }

  const float inv_l = 1.0f / l_i;
  float* dst = Oout + (size_t)(b * S_ + q0 + ro) * HID + h * DH_ + co;
  float4 r0, r1;
  r0.x = Oacc[0]*inv_l; r0.y = Oacc[1]*inv_l; r0.z = Oacc[2]*inv_l; r0.w = Oacc[3]*inv_l;
  r1.x = Oacc[4]*inv_l; r1.y = Oacc[5]*inv_l; r1.z = Oacc[6]*inv_l; r1.w = Oacc[7]*inv_l;
  *(float4*)dst       = r0;
  *(float4*)(dst + 4) = r1;
}

// ---------------------------------------------------------------------------
extern "C" void kernel_launch(void* const* d_in, const int* in_sizes, int n_in,
                              void* d_out, int out_size, void* d_ws, size_t ws_size,
                              hipStream_t stream)
{
  const float* hs    = (const float*)d_in[0];
  const int*   amask = (const int*)  d_in[1];
  const float* Wq    = (const float*)d_in[2];
  const float* bq    = (const float*)d_in[3];
  const float* Wk    = (const float*)d_in[4];
  const float* bk    = (const float*)d_in[5];
  const float* Wv    = (const float*)d_in[6];
  const float* bv    = (const float*)d_in[7];
  const float* Wo    = (const float*)d_in[8];
  const float* bo    = (const float*)d_in[9];
  float* out = (float*)d_out;

  float* Qb = (float*)d_ws;                    // ROWS*HID
  float* Kb = Qb + (size_t)ROWS * HID;         // ROWS*256
  float* Vb = Kb + (size_t)ROWS * (NKV_*DH_);  // ROWS*256
  float* Ab = Vb + (size_t)ROWS * (NKV_*DH_);  // ROWS*HID

  const dim3 blk(256);
  // Q/K/V projections
  gemm_bias_128<<<dim3(HID/128,        ROWS/128), blk, 0, stream>>>(hs, Wq, bq, Qb, ROWS, HID,       HID);
  gemm_bias_128<<<dim3((NKV_*DH_)/128, ROWS/128), blk, 0, stream>>>(hs, Wk, bk, Kb, ROWS, NKV_*DH_,  HID);
  gemm_bias_128<<<dim3((NKV_*DH_)/128, ROWS/128), blk, 0, stream>>>(hs, Wv, bv, Vb, ROWS, NKV_*DH_,  HID);
  // RoPE on Q and K
  {
    int tp_q = ROWS * (HID / 2);
    int tp_k = ROWS * ((NKV_ * DH_) / 2);
    rope_kernel<<<(tp_q + 255) / 256, blk, 0, stream>>>(Qb, HID,       tp_q);
    rope_kernel<<<(tp_k + 255) / 256, blk, 0, stream>>>(Kb, NKV_*DH_,  tp_k);
  }
  // attention
  attn_kernel<<<dim3(S_/32, NH_, B_), blk, 0, stream>>>(Qb, Kb, Vb, amask, Ab);
  // output projection
  gemm_bias_128<<<dim3(HID/128, ROWS/128), blk, 0, stream>>>(Ab, Wo, bo, out, ROWS, HID, HID);
}

// Round 2
// 735.909 us; speedup vs baseline: 1.7167x; 1.7167x over previous
//
#include <hip/hip_runtime.h>
#include <cstddef>
#include <cstdint>

#define B_   2
#define S_   2048
#define HID  1024
#define NH_  16
#define NKV_ 4
#define DH_  64
#define ROWS (B_ * S_)   // 4096

typedef __bf16 bf16_t;
typedef bf16_t bf16x8 __attribute__((ext_vector_type(8)));
typedef float  f32x4  __attribute__((ext_vector_type(4)));

// ---------------------------------------------------------------------------
// GEMM: C[M,N] = A[M,K] @ W[K,N] + bias[N]   (fp32, 128x128 tile, 8x8 micro)
// ---------------------------------------------------------------------------
__global__ __launch_bounds__(256) void gemm_bias_128(
    const float* __restrict__ A, const float* __restrict__ W,
    const float* __restrict__ bias, float* __restrict__ C,
    int M, int N, int K)
{
  __shared__ float As[16][128];
  __shared__ float Bs[16][128];
  const int tid = threadIdx.x;
  const int bm = blockIdx.y * 128;
  const int bn = blockIdx.x * 128;
  const int ar  = tid >> 1;
  const int ak  = (tid & 1) * 8;
  const int bkr = tid >> 4;
  const int bc  = (tid & 15) * 8;
  const int mb  = (tid >> 4) * 8;
  const int nb  = (tid & 15) * 8;

  float acc[8][8];
#pragma unroll
  for (int i = 0; i < 8; ++i)
#pragma unroll
    for (int j = 0; j < 8; ++j) acc[i][j] = 0.f;

  const float* Ap = A + (size_t)(bm + ar) * K + ak;
  const float* Wp = W + (size_t)bkr * N + (bn + bc);

  for (int k0 = 0; k0 < K; k0 += 16) {
    float4 a0 = *(const float4*)(Ap + k0);
    float4 a1 = *(const float4*)(Ap + k0 + 4);
    float4 b0 = *(const float4*)(Wp + (size_t)k0 * N);
    float4 b1 = *(const float4*)(Wp + (size_t)k0 * N + 4);
    __syncthreads();
    As[ak+0][ar] = a0.x; As[ak+1][ar] = a0.y; As[ak+2][ar] = a0.z; As[ak+3][ar] = a0.w;
    As[ak+4][ar] = a1.x; As[ak+5][ar] = a1.y; As[ak+6][ar] = a1.z; As[ak+7][ar] = a1.w;
    *(float4*)&Bs[bkr][bc]   = b0;
    *(float4*)&Bs[bkr][bc+4] = b1;
    __syncthreads();
#pragma unroll
    for (int kk = 0; kk < 16; ++kk) {
      float av[8], bv[8];
      *(float4*)&av[0] = *(const float4*)&As[kk][mb];
      *(float4*)&av[4] = *(const float4*)&As[kk][mb+4];
      *(float4*)&bv[0] = *(const float4*)&Bs[kk][nb];
      *(float4*)&bv[4] = *(const float4*)&Bs[kk][nb+4];
#pragma unroll
      for (int i = 0; i < 8; ++i)
#pragma unroll
        for (int j = 0; j < 8; ++j)
          acc[i][j] = fmaf(av[i], bv[j], acc[i][j]);
    }
  }

  float bvv[8];
#pragma unroll
  for (int j = 0; j < 8; ++j) bvv[j] = bias[bn + nb + j];
#pragma unroll
  for (int i = 0; i < 8; ++i) {
    float4 r0, r1;
    r0.x = acc[i][0] + bvv[0]; r0.y = acc[i][1] + bvv[1];
    r0.z = acc[i][2] + bvv[2]; r0.w = acc[i][3] + bvv[3];
    r1.x = acc[i][4] + bvv[4]; r1.y = acc[i][5] + bvv[5];
    r1.z = acc[i][6] + bvv[6]; r1.w = acc[i][7] + bvv[7];
    float* cp = C + (size_t)(bm + mb + i) * N + (bn + nb);
    *(float4*)cp       = r0;
    *(float4*)(cp + 4) = r1;
  }
}

// ---------------------------------------------------------------------------
// RoPE (in-place) — replicates reference exactly (concat cos/sin layout).
// ---------------------------------------------------------------------------
__global__ void rope_kernel(float* __restrict__ buf, int ncols, int total_pairs)
{
  int idx = blockIdx.x * blockDim.x + threadIdx.x;
  if (idx >= total_pairs) return;
  const int npr = ncols >> 1;
  const int row = idx / npr;
  const int p   = idx - row * npr;
  const int col0 = p * 2;
  const int d0 = col0 & (DH_ - 1);
  const int s  = row & (S_ - 1);
  const float L = 0.51905126482615037f;    // log2(100000)/32
  const float sf = (float)s;
  float ang0 = sf * exp2f(-L * (float)(d0 & 31));
  float ang1 = sf * exp2f(-L * (float)((d0 + 1) & 31));
  float* ptr = buf + (size_t)row * ncols + col0;
  float x0 = ptr[0], x1 = ptr[1];
  ptr[0] = x0 * cosf(ang0) - x1 * sinf(ang0);
  ptr[1] = x1 * cosf(ang1) + x0 * sinf(ang1);
}

// ---------------------------------------------------------------------------
// MFMA flash attention (bf16 compute, fp32 accumulate).
// Block = 256 thr = 4 waves. Block bx handles q-tiles lo=bx (waves 0,1) and
// hi=63-bx (waves 2,3), 16 q-rows per wave — causal load balance.
// K-tiles of 64 keys staged in LDS as bf16: Ks[key][d], Vt[d][key].
// Per wave per tile: 8 MFMA (QK^T) + 8 MFMA (PV), 16x16x32 bf16.
// P round-trips through per-wave LDS (C-layout -> A-layout), no barrier.
// ---------------------------------------------------------------------------
__global__ __launch_bounds__(256, 4) void attn_mfma(
    const float* __restrict__ Q, const float* __restrict__ K,
    const float* __restrict__ V, const int* __restrict__ amask,
    float* __restrict__ Oout)
{
  __shared__ __align__(16) bf16_t Ks[64][72];     // [key][d]
  __shared__ __align__(16) bf16_t Vt[64][72];     // [d][key]
  __shared__ __align__(16) bf16_t Ps[4][16][72];  // per-wave P [q][key]
  __shared__ int Msk[64];

  const int tid  = threadIdx.x;
  const int w    = tid >> 6;
  const int lane = tid & 63;
  const int m    = lane & 15;      // MFMA "n/col" lane id
  const int quad = lane >> 4;      // MFMA quad
  const int lo   = blockIdx.x;
  const int hi   = 63 - blockIdx.x;
  const int h    = blockIdx.y;
  const int b    = blockIdx.z;
  const int kvh  = h >> 2;
  const int qtile = (w < 2) ? lo : hi;
  const int q0w   = qtile * 32 + (w & 1) * 16;   // this wave's first q row (seq idx)

  // --- preload Q A-frags straight from global (A[m][k]: k = quad*8+j) ---
  bf16x8 aq[2];
  {
    const float* qsrc = Q + (size_t)(b * S_ + q0w + m) * HID + h * DH_;
#pragma unroll
    for (int kc = 0; kc < 2; ++kc) {
      const float* p4 = qsrc + kc * 32 + quad * 8;
      float4 f0 = *(const float4*)p4;
      float4 f1 = *(const float4*)(p4 + 4);
      aq[kc][0] = (bf16_t)(f0.x * 0.125f); aq[kc][1] = (bf16_t)(f0.y * 0.125f);
      aq[kc][2] = (bf16_t)(f0.z * 0.125f); aq[kc][3] = (bf16_t)(f0.w * 0.125f);
      aq[kc][4] = (bf16_t)(f1.x * 0.125f); aq[kc][5] = (bf16_t)(f1.y * 0.125f);
      aq[kc][6] = (bf16_t)(f1.z * 0.125f); aq[kc][7] = (bf16_t)(f1.w * 0.125f);
    }
  }

  f32x4 oacc[4];
#pragma unroll
  for (int d = 0; d < 4; ++d) oacc[d] = (f32x4){0.f, 0.f, 0.f, 0.f};
  float m_i[4] = {-1e30f, -1e30f, -1e30f, -1e30f};
  float l_i[4] = {0.f, 0.f, 0.f, 0.f};

  const int qlast = q0w + 15;
  const int nkt = ((hi * 32 + 31) >> 6) + 1;

  // staging indices
  const int skey = tid >> 2;            // K staging: key row
  const int sdc  = (tid & 3) * 16;      // K staging: d chunk
  const int vkey = (lane & 3) * 16 + (lane >> 2);  // V staging: permuted key
  const int vdc  = w * 16;              // V staging: d chunk

  for (int kt = 0; kt < nkt; ++kt) {
    const int kbase = kt * 64;
    __syncthreads();   // previous tile's reads complete
    {
      // K tile -> Ks[key][d] (bf16)
      const float* ks = K + (size_t)(b * S_ + kbase + skey) * (NKV_ * DH_) + kvh * DH_ + sdc;
      float4 f0 = *(const float4*)ks;
      float4 f1 = *(const float4*)(ks + 4);
      float4 f2 = *(const float4*)(ks + 8);
      float4 f3 = *(const float4*)(ks + 12);
      bf16x8 p0, p1;
      p0[0]=(bf16_t)f0.x; p0[1]=(bf16_t)f0.y; p0[2]=(bf16_t)f0.z; p0[3]=(bf16_t)f0.w;
      p0[4]=(bf16_t)f1.x; p0[5]=(bf16_t)f1.y; p0[6]=(bf16_t)f1.z; p0[7]=(bf16_t)f1.w;
      p1[0]=(bf16_t)f2.x; p1[1]=(bf16_t)f2.y; p1[2]=(bf16_t)f2.z; p1[3]=(bf16_t)f2.w;
      p1[4]=(bf16_t)f3.x; p1[5]=(bf16_t)f3.y; p1[6]=(bf16_t)f3.z; p1[7]=(bf16_t)f3.w;
      *(bf16x8*)&Ks[skey][sdc]     = p0;
      *(bf16x8*)&Ks[skey][sdc + 8] = p1;
      // V tile -> Vt[d][key] (transposed; permuted keys spread banks)
      const float* vs = V + (size_t)(b * S_ + kbase + vkey) * (NKV_ * DH_) + kvh * DH_ + vdc;
      float4 v0 = *(const float4*)vs;
      float4 v1 = *(const float4*)(vs + 4);
      float4 v2 = *(const float4*)(vs + 8);
      float4 v3 = *(const float4*)(vs + 12);
      Vt[vdc+ 0][vkey]=(bf16_t)v0.x; Vt[vdc+ 1][vkey]=(bf16_t)v0.y;
      Vt[vdc+ 2][vkey]=(bf16_t)v0.z; Vt[vdc+ 3][vkey]=(bf16_t)v0.w;
      Vt[vdc+ 4][vkey]=(bf16_t)v1.x; Vt[vdc+ 5][vkey]=(bf16_t)v1.y;
      Vt[vdc+ 6][vkey]=(bf16_t)v1.z; Vt[vdc+ 7][vkey]=(bf16_t)v1.w;
      Vt[vdc+ 8][vkey]=(bf16_t)v2.x; Vt[vdc+ 9][vkey]=(bf16_t)v2.y;
      Vt[vdc+10][vkey]=(bf16_t)v2.z; Vt[vdc+11][vkey]=(bf16_t)v2.w;
      Vt[vdc+12][vkey]=(bf16_t)v3.x; Vt[vdc+13][vkey]=(bf16_t)v3.y;
      Vt[vdc+14][vkey]=(bf16_t)v3.z; Vt[vdc+15][vkey]=(bf16_t)v3.w;
      if (tid < 64) Msk[tid] = amask[b * S_ + kbase + tid];
    }
    __syncthreads();

    if (kbase <= qlast) {
      // ---- QK^T ----
      f32x4 sc[4];
#pragma unroll
      for (int cb = 0; cb < 4; ++cb) {
        sc[cb] = (f32x4){0.f, 0.f, 0.f, 0.f};
#pragma unroll
        for (int kc = 0; kc < 2; ++kc) {
          bf16x8 bk = *(const bf16x8*)&Ks[cb * 16 + m][kc * 32 + quad * 8];
          sc[cb] = __builtin_amdgcn_mfma_f32_16x16x32_bf16(aq[kc], bk, sc[cb], 0, 0, 0);
        }
      }
      // ---- masking + online softmax ----
      int kg[4], mok[4];
#pragma unroll
      for (int cb = 0; cb < 4; ++cb) {
        kg[cb]  = kbase + cb * 16 + m;
        mok[cb] = Msk[cb * 16 + m];
      }
      const int qbl = q0w + quad * 4;
      float mrow[4];
#pragma unroll
      for (int r = 0; r < 4; ++r) {
        float v = -1e30f;
#pragma unroll
        for (int cb = 0; cb < 4; ++cb) {
          const bool bad = (kg[cb] > qbl + r) || (mok[cb] == 0);
          v = fmaxf(v, bad ? -1e30f : sc[cb][r]);
        }
        mrow[r] = v;
      }
#pragma unroll
      for (int r = 0; r < 4; ++r) {
        mrow[r] = fmaxf(mrow[r], __shfl_xor(mrow[r], 1));
        mrow[r] = fmaxf(mrow[r], __shfl_xor(mrow[r], 2));
        mrow[r] = fmaxf(mrow[r], __shfl_xor(mrow[r], 4));
        mrow[r] = fmaxf(mrow[r], __shfl_xor(mrow[r], 8));
      }
      float alpha[4], rs[4];
#pragma unroll
      for (int r = 0; r < 4; ++r) {
        const float mn = fmaxf(m_i[r], mrow[r]);
        alpha[r] = __expf(m_i[r] - mn);
        m_i[r] = mn;
        float sum = 0.f;
#pragma unroll
        for (int cb = 0; cb < 4; ++cb) {
          const bool bad = (kg[cb] > qbl + r) || (mok[cb] == 0);
          const float p = bad ? 0.f : __expf(sc[cb][r] - mn);
          sc[cb][r] = p;
          sum += p;
        }
        rs[r] = sum;
      }
#pragma unroll
      for (int r = 0; r < 4; ++r) {
        rs[r] += __shfl_xor(rs[r], 1);
        rs[r] += __shfl_xor(rs[r], 2);
        rs[r] += __shfl_xor(rs[r], 4);
        rs[r] += __shfl_xor(rs[r], 8);
        l_i[r] = l_i[r] * alpha[r] + rs[r];
      }
#pragma unroll
      for (int d = 0; d < 4; ++d)
#pragma unroll
        for (int r = 0; r < 4; ++r) oacc[d][r] *= alpha[r];
      // ---- P: C-layout -> LDS (bf16) ----
#pragma unroll
      for (int cb = 0; cb < 4; ++cb)
#pragma unroll
        for (int r = 0; r < 4; ++r)
          Ps[w][quad * 4 + r][cb * 16 + m] = (bf16_t)sc[cb][r];
      // ---- PV ---- (same-wave RAW on Ps: compiler inserts lgkmcnt wait)
      bf16x8 ap0 = *(const bf16x8*)&Ps[w][m][quad * 8];
      bf16x8 ap1 = *(const bf16x8*)&Ps[w][m][32 + quad * 8];
#pragma unroll
      for (int d = 0; d < 4; ++d) {
        bf16x8 bv0 = *(const bf16x8*)&Vt[d * 16 + m][quad * 8];
        bf16x8 bv1 = *(const bf16x8*)&Vt[d * 16 + m][32 + quad * 8];
        oacc[d] = __builtin_amdgcn_mfma_f32_16x16x32_bf16(ap0, bv0, oacc[d], 0, 0, 0);
        oacc[d] = __builtin_amdgcn_mfma_f32_16x16x32_bf16(ap1, bv1, oacc[d], 0, 0, 0);
      }
    }
  }

  // ---- epilogue: O[row][d] = oacc/l ----
#pragma unroll
  for (int r = 0; r < 4; ++r) {
    const float inv = 1.0f / l_i[r];
    const int qrow = q0w + quad * 4 + r;
    float* dst = Oout + (size_t)(b * S_ + qrow) * HID + h * DH_;
#pragma unroll
    for (int d = 0; d < 4; ++d)
      dst[d * 16 + m] = oacc[d][r] * inv;
  }
}

// ---------------------------------------------------------------------------
extern "C" void kernel_launch(void* const* d_in, const int* in_sizes, int n_in,
                              void* d_out, int out_size, void* d_ws, size_t ws_size,
                              hipStream_t stream)
{
  const float* hs    = (const float*)d_in[0];
  const int*   amask = (const int*)  d_in[1];
  const float* Wq    = (const float*)d_in[2];
  const float* bq    = (const float*)d_in[3];
  const float* Wk    = (const float*)d_in[4];
  const float* bk    = (const float*)d_in[5];
  const float* Wv    = (const float*)d_in[6];
  const float* bv    = (const float*)d_in[7];
  const float* Wo    = (const float*)d_in[8];
  const float* bo    = (const float*)d_in[9];
  float* out = (float*)d_out;

  float* Qb = (float*)d_ws;                    // ROWS*HID
  float* Kb = Qb + (size_t)ROWS * HID;         // ROWS*256
  float* Vb = Kb + (size_t)ROWS * (NKV_*DH_);  // ROWS*256
  float* Ab = Vb + (size_t)ROWS * (NKV_*DH_);  // ROWS*HID

  const dim3 blk(256);
  gemm_bias_128<<<dim3(HID/128,        ROWS/128), blk, 0, stream>>>(hs, Wq, bq, Qb, ROWS, HID,       HID);
  gemm_bias_128<<<dim3((NKV_*DH_)/128, ROWS/128), blk, 0, stream>>>(hs, Wk, bk, Kb, ROWS, NKV_*DH_,  HID);
  gemm_bias_128<<<dim3((NKV_*DH_)/128, ROWS/128), blk, 0, stream>>>(hs, Wv, bv, Vb, ROWS, NKV_*DH_,  HID);
  {
    int tp_q = ROWS * (HID / 2);
    int tp_k = ROWS * ((NKV_ * DH_) / 2);
    rope_kernel<<<(tp_q + 255) / 256, blk, 0, stream>>>(Qb, HID,       tp_q);
    rope_kernel<<<(tp_k + 255) / 256, blk, 0, stream>>>(Kb, NKV_*DH_,  tp_k);
  }
  attn_mfma<<<dim3(S_/64, NH_, B_), blk, 0, stream>>>(Qb, Kb, Vb, amask, Ab);
  gemm_bias_128<<<dim3(HID/128, ROWS/128), blk, 0, stream>>>(Ab, Wo, bo, out, ROWS, HID, HID);
}

// Round 3
// 287.021 us; speedup vs baseline: 4.4015x; 2.5640x over previous
//
#include <hip/hip_runtime.h>
#include <cstddef>
#include <cstdint>

#define B_   2
#define S_   2048
#define HID  1024
#define NH_  16
#define NKV_ 4
#define DH_  64
#define ROWS (B_ * S_)   // 4096
#define NQKV 1536        // 1024 Q + 256 K + 256 V

typedef __bf16 bf16_t;
typedef bf16_t bf16x8 __attribute__((ext_vector_type(8)));
typedef float  f32x4  __attribute__((ext_vector_type(4)));

typedef __attribute__((address_space(1))) const uint32_t gu32_t;
typedef __attribute__((address_space(3))) uint32_t lu32_t;

__device__ __forceinline__ void gl_lds16(const bf16_t* g, bf16_t* l) {
  __builtin_amdgcn_global_load_lds((gu32_t*)g, (lu32_t*)l, 16, 0, 0);
}

// ---------------------------------------------------------------------------
// cast fp32 -> bf16 (8 elems/thread, coalesced)
// ---------------------------------------------------------------------------
__global__ void cast_bf16(const float* __restrict__ in, bf16_t* __restrict__ out, int n)
{
  int i = (blockIdx.x * blockDim.x + threadIdx.x) * 8;
  if (i >= n) return;
  float4 a = *(const float4*)(in + i);
  float4 b = *(const float4*)(in + i + 4);
  bf16x8 o;
  o[0]=(bf16_t)a.x; o[1]=(bf16_t)a.y; o[2]=(bf16_t)a.z; o[3]=(bf16_t)a.w;
  o[4]=(bf16_t)b.x; o[5]=(bf16_t)b.y; o[6]=(bf16_t)b.z; o[7]=(bf16_t)b.w;
  *(bf16x8*)(out + i) = o;
}

// ---------------------------------------------------------------------------
// transpose + cast: in [K][N] fp32 -> out [N][K] bf16.  32x32 tiles, 32x8 thr.
// ---------------------------------------------------------------------------
__global__ void transpose_cast(const float* __restrict__ in, bf16_t* __restrict__ out,
                               int K, int N)
{
  __shared__ bf16_t T[32][33];
  const int n0 = blockIdx.x * 32, k0 = blockIdx.y * 32;
  const int tx = threadIdx.x, ty = threadIdx.y;
#pragma unroll
  for (int i = 0; i < 4; ++i)
    T[ty + i*8][tx] = (bf16_t)in[(size_t)(k0 + ty + i*8) * N + n0 + tx];
  __syncthreads();
#pragma unroll
  for (int i = 0; i < 4; ++i)
    out[(size_t)(n0 + ty + i*8) * K + k0 + tx] = T[tx][ty + i*8];
}

__global__ void concat_bias(const float* __restrict__ bq, const float* __restrict__ bk,
                            const float* __restrict__ bv, float* __restrict__ out)
{
  int i = blockIdx.x * 256 + threadIdx.x;
  if (i >= NQKV) return;
  out[i] = (i < 1024) ? bq[i] : ((i < 1280) ? bk[i - 1024] : bv[i - 1280]);
}

// ---------------------------------------------------------------------------
// bf16 MFMA GEMM (m97 pattern): C[M,N] = A[M,K]@Bt[N,K]^T + bias.
// 128x128 tile, BK=64, 256 thr = 4 waves (2x2 of 64x64), global_load_lds w=16.
// ---------------------------------------------------------------------------
__global__ __launch_bounds__(256, 2) void gemm_bt_bf16(
    const bf16_t* __restrict__ A, const bf16_t* __restrict__ Bt,
    const float* __restrict__ bias, float* __restrict__ C,
    int M, int N, int K)
{
  __shared__ bf16_t As[128 * 64];
  __shared__ bf16_t Bs[128 * 64];
  const int tid  = threadIdx.x;
  const int w    = tid >> 6;
  const int lane = tid & 63;
  const int m    = lane & 15;
  const int quad = lane >> 4;
  const int wm   = w >> 1, wn = w & 1;
  const size_t bm = (size_t)blockIdx.y * 128;
  const size_t bn = (size_t)blockIdx.x * 128;

  const int srow = w * 8 + (lane >> 3);     // +i*32 per staging instr
  const int scol = (lane & 7) * 8;
  const bf16_t* Ag = A  + (bm + srow) * K + scol;
  const bf16_t* Bg = Bt + (bn + srow) * K + scol;

  f32x4 acc[4][4];
#pragma unroll
  for (int i = 0; i < 4; ++i)
#pragma unroll
    for (int j = 0; j < 4; ++j) acc[i][j] = (f32x4){0.f, 0.f, 0.f, 0.f};

  for (int k0 = 0; k0 < K; k0 += 64) {
    __syncthreads();   // previous iter's LDS reads complete
#pragma unroll
    for (int i = 0; i < 4; ++i) {
      gl_lds16(Ag + (size_t)(i * 32) * K + k0, &As[(w * 8 + i * 32) * 64]);
      gl_lds16(Bg + (size_t)(i * 32) * K + k0, &Bs[(w * 8 + i * 32) * 64]);
    }
    __syncthreads();   // drains vmcnt (global_load_lds) + lgkm
#pragma unroll
    for (int ks = 0; ks < 2; ++ks) {
      bf16x8 af[4], bfr[4];
#pragma unroll
      for (int mt = 0; mt < 4; ++mt)
        af[mt] = *(const bf16x8*)&As[(wm * 64 + mt * 16 + m) * 64 + ks * 32 + quad * 8];
#pragma unroll
      for (int nt = 0; nt < 4; ++nt)
        bfr[nt] = *(const bf16x8*)&Bs[(wn * 64 + nt * 16 + m) * 64 + ks * 32 + quad * 8];
#pragma unroll
      for (int mt = 0; mt < 4; ++mt)
#pragma unroll
        for (int nt = 0; nt < 4; ++nt)
          acc[mt][nt] = __builtin_amdgcn_mfma_f32_16x16x32_bf16(af[mt], bfr[nt], acc[mt][nt], 0, 0, 0);
    }
  }

#pragma unroll
  for (int mt = 0; mt < 4; ++mt) {
    const size_t row = bm + wm * 64 + mt * 16 + quad * 4;
#pragma unroll
    for (int nt = 0; nt < 4; ++nt) {
      const size_t col = bn + wn * 64 + nt * 16 + m;
      const float bb = bias[col];
#pragma unroll
      for (int r = 0; r < 4; ++r)
        C[(row + r) * N + col] = acc[mt][nt][r] + bb;
    }
  }
}

// ---------------------------------------------------------------------------
// RoPE in-place on fused QKV fp32 buffer [ROWS][NQKV]; cols 0..1279 (Q||K).
// d0 = col & 63 works for both regions (1024 is a multiple of 64).
// ---------------------------------------------------------------------------
__global__ void rope_kernel(float* __restrict__ buf, int total_pairs)
{
  int idx = blockIdx.x * blockDim.x + threadIdx.x;
  if (idx >= total_pairs) return;
  const int row = idx / 640;
  const int col0 = (idx - row * 640) * 2;    // 0..1278
  const int d0 = col0 & (DH_ - 1);
  const int s  = row & (S_ - 1);
  const float L = 0.51905126482615037f;      // log2(100000)/32
  const float sf = (float)s;
  float ang0 = sf * exp2f(-L * (float)(d0 & 31));
  float ang1 = sf * exp2f(-L * (float)((d0 + 1) & 31));
  float* ptr = buf + (size_t)row * NQKV + col0;
  float x0 = ptr[0], x1 = ptr[1];
  ptr[0] = x0 * cosf(ang0) - x1 * sinf(ang0);
  ptr[1] = x1 * cosf(ang1) + x0 * sinf(ang1);
}

// ---------------------------------------------------------------------------
// MFMA flash attention reading fused QKV fp32 [ROWS][NQKV], writing bf16 out.
// Q at col h*64, K at 1024+kvh*64, V at 1280+kvh*64.
// ---------------------------------------------------------------------------
__global__ __launch_bounds__(256, 4) void attn_mfma(
    const float* __restrict__ QKV, const int* __restrict__ amask,
    bf16_t* __restrict__ Oout)
{
  __shared__ __align__(16) bf16_t Ks[64][72];     // [key][d]
  __shared__ __align__(16) bf16_t Vt[64][72];     // [d][key]
  __shared__ __align__(16) bf16_t Ps[4][16][72];  // per-wave P [q][key]
  __shared__ int Msk[64];

  const int tid  = threadIdx.x;
  const int w    = tid >> 6;
  const int lane = tid & 63;
  const int m    = lane & 15;
  const int quad = lane >> 4;
  const int lo   = blockIdx.x;
  const int hi   = 63 - blockIdx.x;
  const int h    = blockIdx.y;
  const int b    = blockIdx.z;
  const int kvh  = h >> 2;
  const int qtile = (w < 2) ? lo : hi;
  const int q0w   = qtile * 32 + (w & 1) * 16;

  // Q A-frags from global (A[m][k]: k = quad*8+j), pre-scaled by 1/8
  bf16x8 aq[2];
  {
    const float* qsrc = QKV + (size_t)(b * S_ + q0w + m) * NQKV + h * DH_;
#pragma unroll
    for (int kc = 0; kc < 2; ++kc) {
      const float* p4 = qsrc + kc * 32 + quad * 8;
      float4 f0 = *(const float4*)p4;
      float4 f1 = *(const float4*)(p4 + 4);
      aq[kc][0] = (bf16_t)(f0.x * 0.125f); aq[kc][1] = (bf16_t)(f0.y * 0.125f);
      aq[kc][2] = (bf16_t)(f0.z * 0.125f); aq[kc][3] = (bf16_t)(f0.w * 0.125f);
      aq[kc][4] = (bf16_t)(f1.x * 0.125f); aq[kc][5] = (bf16_t)(f1.y * 0.125f);
      aq[kc][6] = (bf16_t)(f1.z * 0.125f); aq[kc][7] = (bf16_t)(f1.w * 0.125f);
    }
  }

  f32x4 oacc[4];
#pragma unroll
  for (int d = 0; d < 4; ++d) oacc[d] = (f32x4){0.f, 0.f, 0.f, 0.f};
  float m_i[4] = {-1e30f, -1e30f, -1e30f, -1e30f};
  float l_i[4] = {0.f, 0.f, 0.f, 0.f};

  const int qlast = q0w + 15;
  const int nkt = ((hi * 32 + 31) >> 6) + 1;

  const int skey = tid >> 2;
  const int sdc  = (tid & 3) * 16;
  const int vkey = (lane & 3) * 16 + (lane >> 2);
  const int vdc  = w * 16;

  for (int kt = 0; kt < nkt; ++kt) {
    const int kbase = kt * 64;
    __syncthreads();
    {
      const float* ks = QKV + (size_t)(b * S_ + kbase + skey) * NQKV + 1024 + kvh * DH_ + sdc;
      float4 f0 = *(const float4*)ks;
      float4 f1 = *(const float4*)(ks + 4);
      float4 f2 = *(const float4*)(ks + 8);
      float4 f3 = *(const float4*)(ks + 12);
      bf16x8 p0, p1;
      p0[0]=(bf16_t)f0.x; p0[1]=(bf16_t)f0.y; p0[2]=(bf16_t)f0.z; p0[3]=(bf16_t)f0.w;
      p0[4]=(bf16_t)f1.x; p0[5]=(bf16_t)f1.y; p0[6]=(bf16_t)f1.z; p0[7]=(bf16_t)f1.w;
      p1[0]=(bf16_t)f2.x; p1[1]=(bf16_t)f2.y; p1[2]=(bf16_t)f2.z; p1[3]=(bf16_t)f2.w;
      p1[4]=(bf16_t)f3.x; p1[5]=(bf16_t)f3.y; p1[6]=(bf16_t)f3.z; p1[7]=(bf16_t)f3.w;
      *(bf16x8*)&Ks[skey][sdc]     = p0;
      *(bf16x8*)&Ks[skey][sdc + 8] = p1;
      const float* vs = QKV + (size_t)(b * S_ + kbase + vkey) * NQKV + 1280 + kvh * DH_ + vdc;
      float4 v0 = *(const float4*)vs;
      float4 v1 = *(const float4*)(vs + 4);
      float4 v2 = *(const float4*)(vs + 8);
      float4 v3 = *(const float4*)(vs + 12);
      Vt[vdc+ 0][vkey]=(bf16_t)v0.x; Vt[vdc+ 1][vkey]=(bf16_t)v0.y;
      Vt[vdc+ 2][vkey]=(bf16_t)v0.z; Vt[vdc+ 3][vkey]=(bf16_t)v0.w;
      Vt[vdc+ 4][vkey]=(bf16_t)v1.x; Vt[vdc+ 5][vkey]=(bf16_t)v1.y;
      Vt[vdc+ 6][vkey]=(bf16_t)v1.z; Vt[vdc+ 7][vkey]=(bf16_t)v1.w;
      Vt[vdc+ 8][vkey]=(bf16_t)v2.x; Vt[vdc+ 9][vkey]=(bf16_t)v2.y;
      Vt[vdc+10][vkey]=(bf16_t)v2.z; Vt[vdc+11][vkey]=(bf16_t)v2.w;
      Vt[vdc+12][vkey]=(bf16_t)v3.x; Vt[vdc+13][vkey]=(bf16_t)v3.y;
      Vt[vdc+14][vkey]=(bf16_t)v3.z; Vt[vdc+15][vkey]=(bf16_t)v3.w;
      if (tid < 64) Msk[tid] = amask[b * S_ + kbase + tid];
    }
    __syncthreads();

    if (kbase <= qlast) {
      f32x4 sc[4];
#pragma unroll
      for (int cb = 0; cb < 4; ++cb) {
        sc[cb] = (f32x4){0.f, 0.f, 0.f, 0.f};
#pragma unroll
        for (int kc = 0; kc < 2; ++kc) {
          bf16x8 bk = *(const bf16x8*)&Ks[cb * 16 + m][kc * 32 + quad * 8];
          sc[cb] = __builtin_amdgcn_mfma_f32_16x16x32_bf16(aq[kc], bk, sc[cb], 0, 0, 0);
        }
      }
      int kg[4], mok[4];
#pragma unroll
      for (int cb = 0; cb < 4; ++cb) {
        kg[cb]  = kbase + cb * 16 + m;
        mok[cb] = Msk[cb * 16 + m];
      }
      const int qbl = q0w + quad * 4;
      float mrow[4];
#pragma unroll
      for (int r = 0; r < 4; ++r) {
        float v = -1e30f;
#pragma unroll
        for (int cb = 0; cb < 4; ++cb) {
          const bool bad = (kg[cb] > qbl + r) || (mok[cb] == 0);
          v = fmaxf(v, bad ? -1e30f : sc[cb][r]);
        }
        mrow[r] = v;
      }
#pragma unroll
      for (int r = 0; r < 4; ++r) {
        mrow[r] = fmaxf(mrow[r], __shfl_xor(mrow[r], 1));
        mrow[r] = fmaxf(mrow[r], __shfl_xor(mrow[r], 2));
        mrow[r] = fmaxf(mrow[r], __shfl_xor(mrow[r], 4));
        mrow[r] = fmaxf(mrow[r], __shfl_xor(mrow[r], 8));
      }
      float alpha[4], rs[4];
#pragma unroll
      for (int r = 0; r < 4; ++r) {
        const float mn = fmaxf(m_i[r], mrow[r]);
        alpha[r] = __expf(m_i[r] - mn);
        m_i[r] = mn;
        float sum = 0.f;
#pragma unroll
        for (int cb = 0; cb < 4; ++cb) {
          const bool bad = (kg[cb] > qbl + r) || (mok[cb] == 0);
          const float p = bad ? 0.f : __expf(sc[cb][r] - mn);
          sc[cb][r] = p;
          sum += p;
        }
        rs[r] = sum;
      }
#pragma unroll
      for (int r = 0; r < 4; ++r) {
        rs[r] += __shfl_xor(rs[r], 1);
        rs[r] += __shfl_xor(rs[r], 2);
        rs[r] += __shfl_xor(rs[r], 4);
        rs[r] += __shfl_xor(rs[r], 8);
        l_i[r] = l_i[r] * alpha[r] + rs[r];
      }
#pragma unroll
      for (int d = 0; d < 4; ++d)
#pragma unroll
        for (int r = 0; r < 4; ++r) oacc[d][r] *= alpha[r];
#pragma unroll
      for (int cb = 0; cb < 4; ++cb)
#pragma unroll
        for (int r = 0; r < 4; ++r)
          Ps[w][quad * 4 + r][cb * 16 + m] = (bf16_t)sc[cb][r];
      bf16x8 ap0 = *(const bf16x8*)&Ps[w][m][quad * 8];
      bf16x8 ap1 = *(const bf16x8*)&Ps[w][m][32 + quad * 8];
#pragma unroll
      for (int d = 0; d < 4; ++d) {
        bf16x8 bv0 = *(const bf16x8*)&Vt[d * 16 + m][quad * 8];
        bf16x8 bv1 = *(const bf16x8*)&Vt[d * 16 + m][32 + quad * 8];
        oacc[d] = __builtin_amdgcn_mfma_f32_16x16x32_bf16(ap0, bv0, oacc[d], 0, 0, 0);
        oacc[d] = __builtin_amdgcn_mfma_f32_16x16x32_bf16(ap1, bv1, oacc[d], 0, 0, 0);
      }
    }
  }

#pragma unroll
  for (int r = 0; r < 4; ++r) {
    const float inv = 1.0f / l_i[r];
    const int qrow = q0w + quad * 4 + r;
    bf16_t* dst = Oout + (size_t)(b * S_ + qrow) * HID + h * DH_;
#pragma unroll
    for (int d = 0; d < 4; ++d)
      dst[d * 16 + m] = (bf16_t)(oacc[d][r] * inv);
  }
}

// ---------------------------------------------------------------------------
extern "C" void kernel_launch(void* const* d_in, const int* in_sizes, int n_in,
                              void* d_out, int out_size, void* d_ws, size_t ws_size,
                              hipStream_t stream)
{
  const float* hs    = (const float*)d_in[0];
  const int*   amask = (const int*)  d_in[1];
  const float* Wq    = (const float*)d_in[2];
  const float* bq    = (const float*)d_in[3];
  const float* Wk    = (const float*)d_in[4];
  const float* bk    = (const float*)d_in[5];
  const float* Wv    = (const float*)d_in[6];
  const float* bv    = (const float*)d_in[7];
  const float* Wo    = (const float*)d_in[8];
  const float* bo    = (const float*)d_in[9];
  float* out = (float*)d_out;

  // workspace layout (~38.8 MB)
  float*  QKV = (float*)d_ws;                          // ROWS*NQKV f32
  bf16_t* hsb = (bf16_t*)(QKV + (size_t)ROWS * NQKV);  // ROWS*HID bf16 (aliased attn-out)
  bf16_t* Wt  = hsb + (size_t)ROWS * HID;              // NQKV*HID bf16 (W^T fused)
  bf16_t* Wot = Wt + (size_t)NQKV * HID;               // HID*HID bf16
  float*  ball= (float*)(Wot + (size_t)HID * HID);     // NQKV f32
  bf16_t* Ab  = hsb;                                   // alias: attn out (bf16)

  // prep
  cast_bf16<<<(ROWS * HID / 8 + 255) / 256, 256, 0, stream>>>(hs, hsb, ROWS * HID);
  transpose_cast<<<dim3(HID/32, HID/32), dim3(32,8), 0, stream>>>(Wq, Wt,               HID, HID);
  transpose_cast<<<dim3(256/32, HID/32), dim3(32,8), 0, stream>>>(Wk, Wt + 1024*HID,    HID, 256);
  transpose_cast<<<dim3(256/32, HID/32), dim3(32,8), 0, stream>>>(Wv, Wt + 1280*HID,    HID, 256);
  transpose_cast<<<dim3(HID/32, HID/32), dim3(32,8), 0, stream>>>(Wo, Wot,              HID, HID);
  concat_bias<<<(NQKV + 255) / 256, 256, 0, stream>>>(bq, bk, bv, ball);

  // fused QKV projection
  gemm_bt_bf16<<<dim3(NQKV/128, ROWS/128), 256, 0, stream>>>(hsb, Wt, ball, QKV, ROWS, NQKV, HID);
  // RoPE on Q||K region
  {
    int tp = ROWS * 640;
    rope_kernel<<<(tp + 255) / 256, 256, 0, stream>>>(QKV, tp);
  }
  // attention (writes bf16)
  attn_mfma<<<dim3(S_/64, NH_, B_), 256, 0, stream>>>(QKV, amask, Ab);
  // output projection
  gemm_bt_bf16<<<dim3(HID/128, ROWS/128), 256, 0, stream>>>(Ab, Wot, bo, out, ROWS, HID, HID);
}

// Round 4
// 228.089 us; speedup vs baseline: 5.5387x; 1.2584x over previous
//
#include <hip/hip_runtime.h>
#include <cstddef>
#include <cstdint>

#define B_   2
#define S_   2048
#define HID  1024
#define NH_  16
#define NKV_ 4
#define DH_  64
#define ROWS (B_ * S_)   // 4096
#define NQKV 1536        // 1024 Q + 256 K + 256 V

typedef __bf16 bf16_t;
typedef _Float16 f16_t;
typedef bf16_t bf16x8 __attribute__((ext_vector_type(8)));
typedef bf16_t bf16x4 __attribute__((ext_vector_type(4)));
typedef f16_t  f16x8  __attribute__((ext_vector_type(8)));
typedef f16_t  f16x4  __attribute__((ext_vector_type(4)));
typedef float  f32x4  __attribute__((ext_vector_type(4)));

typedef __attribute__((address_space(1))) const uint32_t gu32_t;
typedef __attribute__((address_space(3))) uint32_t lu32_t;

__device__ __forceinline__ void gl_lds16(const void* g, void* l) {
  __builtin_amdgcn_global_load_lds((gu32_t*)g, (lu32_t*)l, 16, 0, 0);
}

// ---------------------------------------------------------------------------
// cast fp32 -> bf16 (8 elems/thread, coalesced)
// ---------------------------------------------------------------------------
__global__ void cast_bf16(const float* __restrict__ in, bf16_t* __restrict__ out, int n)
{
  int i = (blockIdx.x * blockDim.x + threadIdx.x) * 8;
  if (i >= n) return;
  float4 a = *(const float4*)(in + i);
  float4 b = *(const float4*)(in + i + 4);
  bf16x8 o;
  o[0]=(bf16_t)a.x; o[1]=(bf16_t)a.y; o[2]=(bf16_t)a.z; o[3]=(bf16_t)a.w;
  o[4]=(bf16_t)b.x; o[5]=(bf16_t)b.y; o[6]=(bf16_t)b.z; o[7]=(bf16_t)b.w;
  *(bf16x8*)(out + i) = o;
}

// ---------------------------------------------------------------------------
// fused weight prep: transpose+cast Wq/Wk/Wv -> Wt[1536][1024], Wo -> Wot,
// concat biases. blocks: 0..1023 Wq | ..1279 Wk | ..1535 Wv | ..2559 Wo | +6 bias
// ---------------------------------------------------------------------------
__global__ void prep_w(const float* __restrict__ Wq, const float* __restrict__ Wk,
                       const float* __restrict__ Wv, const float* __restrict__ Wo,
                       const float* __restrict__ bq, const float* __restrict__ bk,
                       const float* __restrict__ bv,
                       bf16_t* __restrict__ Wt, bf16_t* __restrict__ Wot,
                       float* __restrict__ ball)
{
  const int bid = blockIdx.x;
  if (bid >= 2560) {
    int i = (bid - 2560) * 256 + threadIdx.x;
    if (i < NQKV) ball[i] = (i < 1024) ? bq[i] : ((i < 1280) ? bk[i-1024] : bv[i-1280]);
    return;
  }
  const float* src; bf16_t* dst; int N, n0, k0;
  if (bid < 1024)      { src = Wq; dst = Wt;            N = 1024; int t = bid;      n0=(t&31)*32; k0=(t>>5)*32; }
  else if (bid < 1280) { src = Wk; dst = Wt + 1024*HID; N = 256;  int t = bid-1024; n0=(t&7)*32;  k0=(t>>3)*32; }
  else if (bid < 1536) { src = Wv; dst = Wt + 1280*HID; N = 256;  int t = bid-1280; n0=(t&7)*32;  k0=(t>>3)*32; }
  else                 { src = Wo; dst = Wot;           N = 1024; int t = bid-1536; n0=(t&31)*32; k0=(t>>5)*32; }
  __shared__ bf16_t T[32][33];
  const int tx = threadIdx.x & 31, ty = threadIdx.x >> 5;
#pragma unroll
  for (int i = 0; i < 4; ++i)
    T[ty + i*8][tx] = (bf16_t)src[(size_t)(k0 + ty + i*8) * N + n0 + tx];
  __syncthreads();
#pragma unroll
  for (int i = 0; i < 4; ++i)
    dst[(size_t)(n0 + ty + i*8) * HID + k0 + tx] = T[tx][ty + i*8];
}

// ---------------------------------------------------------------------------
// bf16 MFMA GEMM: C[M,N] = A[M,K]@Bt[N,K]^T + bias. 128x128 tile, BK=64,
// 256 thr = 4 waves. MFMA operands swapped (D[m=col][n=row]) so each lane
// holds 4 consecutive output cols -> float4 C-stores.
// ---------------------------------------------------------------------------
__global__ __launch_bounds__(256, 2) void gemm_bt_bf16(
    const bf16_t* __restrict__ A, const bf16_t* __restrict__ Bt,
    const float* __restrict__ bias, float* __restrict__ C,
    int M, int N, int K)
{
  __shared__ bf16_t As[128 * 64];
  __shared__ bf16_t Bs[128 * 64];
  const int tid  = threadIdx.x;
  const int w    = tid >> 6;
  const int lane = tid & 63;
  const int m    = lane & 15;
  const int quad = lane >> 4;
  const int wm   = w >> 1, wn = w & 1;
  const size_t bm = (size_t)blockIdx.y * 128;
  const size_t bn = (size_t)blockIdx.x * 128;

  const int srow = w * 8 + (lane >> 3);
  const int scol = (lane & 7) * 8;
  const bf16_t* Ag = A  + (bm + srow) * K + scol;
  const bf16_t* Bg = Bt + (bn + srow) * K + scol;

  f32x4 acc[4][4];
#pragma unroll
  for (int i = 0; i < 4; ++i)
#pragma unroll
    for (int j = 0; j < 4; ++j) acc[i][j] = (f32x4){0.f, 0.f, 0.f, 0.f};

  for (int k0 = 0; k0 < K; k0 += 64) {
    __syncthreads();
#pragma unroll
    for (int i = 0; i < 4; ++i) {
      gl_lds16(Ag + (size_t)(i * 32) * K + k0, &As[(w * 8 + i * 32) * 64]);
      gl_lds16(Bg + (size_t)(i * 32) * K + k0, &Bs[(w * 8 + i * 32) * 64]);
    }
    __syncthreads();
#pragma unroll
    for (int ks = 0; ks < 2; ++ks) {
      bf16x8 af[4], bfr[4];
#pragma unroll
      for (int mt = 0; mt < 4; ++mt)
        af[mt] = *(const bf16x8*)&As[(wm * 64 + mt * 16 + m) * 64 + ks * 32 + quad * 8];
#pragma unroll
      for (int nt = 0; nt < 4; ++nt)
        bfr[nt] = *(const bf16x8*)&Bs[(wn * 64 + nt * 16 + m) * 64 + ks * 32 + quad * 8];
#pragma unroll
      for (int mt = 0; mt < 4; ++mt)
#pragma unroll
        for (int nt = 0; nt < 4; ++nt)
          acc[mt][nt] = __builtin_amdgcn_mfma_f32_16x16x32_bf16(bfr[nt], af[mt], acc[mt][nt], 0, 0, 0);
    }
  }

#pragma unroll
  for (int mt = 0; mt < 4; ++mt) {
    const size_t row = bm + wm * 64 + mt * 16 + m;
#pragma unroll
    for (int nt = 0; nt < 4; ++nt) {
      const size_t col = bn + wn * 64 + nt * 16 + quad * 4;
      float4 bb = *(const float4*)&bias[col];
      float4 o;
      o.x = acc[mt][nt][0] + bb.x; o.y = acc[mt][nt][1] + bb.y;
      o.z = acc[mt][nt][2] + bb.z; o.w = acc[mt][nt][3] + bb.w;
      *(float4*)&C[row * N + col] = o;
    }
  }
}

// ---------------------------------------------------------------------------
// prep_q: RoPE + scale(1/8) + cast Q region of QKV fp32 -> Qb bf16 [ROWS][1024]
// ---------------------------------------------------------------------------
__global__ void prep_q(const float* __restrict__ QKV, bf16_t* __restrict__ Qb)
{
  const int t = blockIdx.x * 256 + threadIdx.x;     // ROWS*256 threads
  const int row = t >> 8, c4 = (t & 255) * 4;
  float4 x = *(const float4*)(QKV + (size_t)row * NQKV + c4);
  const int d = c4 & (DH_ - 1);
  const int s = row & (S_ - 1);
  const float L = 0.51905126482615037f;             // log2(1e5)/32
  const float sf = (float)s;
  float a0 = sf * exp2f(-L * (float)( d      & 31));
  float a1 = sf * exp2f(-L * (float)((d + 1) & 31));
  float a2 = sf * exp2f(-L * (float)((d + 2) & 31));
  float a3 = sf * exp2f(-L * (float)((d + 3) & 31));
  float y0 = x.x * cosf(a0) - x.y * sinf(a0);
  float y1 = x.y * cosf(a1) + x.x * sinf(a1);
  float y2 = x.z * cosf(a2) - x.w * sinf(a2);
  float y3 = x.w * cosf(a3) + x.z * sinf(a3);
  bf16x4 o;
  o[0] = (bf16_t)(y0 * 0.125f); o[1] = (bf16_t)(y1 * 0.125f);
  o[2] = (bf16_t)(y2 * 0.125f); o[3] = (bf16_t)(y3 * 0.125f);
  *(bf16x4*)(Qb + (size_t)row * HID + c4) = o;
}

// ---------------------------------------------------------------------------
// prep_kv: build per-(b,kvh,kt) 8KB LDS-ready tile images.
//  K image (bf16, RoPE'd): row key(64) x 8 chunks of 16B; chunk slot c holds
//    source d-chunk c^(key&7)  (XOR swizzle).
//  V image (f16): row d(64) x 8 chunks; slot c holds source key-chunk c^(d&7).
// ---------------------------------------------------------------------------
__global__ void prep_kv(const float* __restrict__ QKV,
                        bf16_t* __restrict__ Kt2, f16_t* __restrict__ Vt2)
{
  const int kt = blockIdx.x, kvh = blockIdx.y, b = blockIdx.z;
  const int t = threadIdx.x;
  const size_t img = ((size_t)(b * NKV_ + kvh) * 32 + kt) * 4096;
  const float L = 0.51905126482615037f;
  {
    const int key = t & 63, cg = t >> 6;            // cg: d-chunk pair, d = 16cg..+15
    const int srow = kt * 64 + key;
    const float* p = QKV + (size_t)(b * S_ + srow) * NQKV + 1024 + kvh * DH_ + cg * 16;
    float4 q0 = *(const float4*)p,       q1 = *(const float4*)(p + 4);
    float4 q2 = *(const float4*)(p + 8), q3 = *(const float4*)(p + 12);
    float v[16] = {q0.x,q0.y,q0.z,q0.w, q1.x,q1.y,q1.z,q1.w,
                   q2.x,q2.y,q2.z,q2.w, q3.x,q3.y,q3.z,q3.w};
    const float sf = (float)srow;
    bf16x8 o0, o1;
#pragma unroll
    for (int j = 0; j < 8; ++j) {
      const int d = cg * 16 + 2 * j;
      float a0 = sf * exp2f(-L * (float)( d      & 31));
      float a1 = sf * exp2f(-L * (float)((d + 1) & 31));
      float y0 = v[2*j] * cosf(a0) - v[2*j+1] * sinf(a0);
      float y1 = v[2*j+1] * cosf(a1) + v[2*j] * sinf(a1);
      if (j < 4) { o0[2*j] = (bf16_t)y0; o0[2*j+1] = (bf16_t)y1; }
      else       { o1[2*(j-4)] = (bf16_t)y0; o1[2*(j-4)+1] = (bf16_t)y1; }
    }
    const int s0 = (2*cg) ^ (key & 7), s1 = (2*cg + 1) ^ (key & 7);
    *(bf16x8*)(Kt2 + img + key * 64 + s0 * 8) = o0;
    *(bf16x8*)(Kt2 + img + key * 64 + s1 * 8) = o1;
  }
  {
    const int d = t & 63, cg = t >> 6;              // cg: key-chunk pair, keys 16cg..+15
    const float* p = QKV + (size_t)(b * S_ + kt * 64 + cg * 16) * NQKV + 1280 + kvh * DH_ + d;
    f16x8 o0, o1;
#pragma unroll
    for (int u = 0; u < 8; ++u)  o0[u] = (f16_t)p[(size_t)u * NQKV];
#pragma unroll
    for (int u = 0; u < 8; ++u)  o1[u] = (f16_t)p[(size_t)(u + 8) * NQKV];
    const int s0 = (2*cg) ^ (d & 7), s1 = (2*cg + 1) ^ (d & 7);
    *(f16x8*)(Vt2 + img + d * 64 + s0 * 8) = o0;
    *(f16x8*)(Vt2 + img + d * 64 + s1 * 8) = o1;
  }
}

// ---------------------------------------------------------------------------
// attn_v2: S^T = K.Q^T (bf16 x32 MFMA), online softmax per-lane (q=lane&15),
// PV as O^T = V^T.P^T via 16x16x16 f16 MFMA with P staying in registers.
// Wave = 32 q-rows (2 m-tiles); block = 4 waves, lo/hi causal pairing.
// ---------------------------------------------------------------------------
__global__ __launch_bounds__(256, 2) void attn_v2(
    const bf16_t* __restrict__ Qb, const bf16_t* __restrict__ Kt2,
    const f16_t* __restrict__ Vt2, const int* __restrict__ amask,
    bf16_t* __restrict__ Ab)
{
  __shared__ __align__(16) bf16_t Ks[64 * 64];   // swizzled K tile image
  __shared__ __align__(16) f16_t  Vs[64 * 64];   // swizzled V^T tile image

  const int tid  = threadIdx.x;
  const int w    = tid >> 6;
  const int lane = tid & 63;
  const int m    = lane & 15;
  const int quad = lane >> 4;
  const int h    = blockIdx.y;
  const int b    = blockIdx.z;
  const int kvh  = h >> 2;
  const int bx   = blockIdx.x;
  // q-tile (32 rows) per wave, lo/hi pairing for causal balance
  const int qt   = (w == 0) ? 2*bx : (w == 1) ? 2*bx + 1 : (w == 2) ? 62 - 2*bx : 63 - 2*bx;
  const int q0w  = qt * 32;
  const int qlast = q0w + 31;
  const int nkt  = 32 - bx;     // covers max wave (63-2bx)*32+31

  // Q fragments (B-operand layout): aq[mt][kc]
  bf16x8 aq[2][2];
#pragma unroll
  for (int mt = 0; mt < 2; ++mt)
#pragma unroll
    for (int kc = 0; kc < 2; ++kc)
      aq[mt][kc] = *(const bf16x8*)&Qb[(size_t)(b * S_ + q0w + mt*16 + m) * HID
                                        + h * DH_ + kc * 32 + quad * 8];

  f32x4 oacc[2][4];
#pragma unroll
  for (int mt = 0; mt < 2; ++mt)
#pragma unroll
    for (int d = 0; d < 4; ++d) oacc[mt][d] = (f32x4){0.f,0.f,0.f,0.f};
  float m_i[2] = {-1e30f, -1e30f}, l_i[2] = {0.f, 0.f};

  const size_t imgbase = ((size_t)(b * NKV_ + kvh) * 32) * 4096;
  const bf16_t* Kg = Kt2 + imgbase;
  const f16_t*  Vg = Vt2 + imgbase;
  const int x0 = quad ^ (m & 7);          // QK read slot, kc=0
  const int x1 = (4 + quad) ^ (m & 7);    // kc=1

  for (int kt = 0; kt < nkt; ++kt) {
    const int kbase = kt * 64;
    __syncthreads();
    gl_lds16(Kg + (size_t)kt * 4096 + (2*w)   * 512 + lane * 8, &Ks[(2*w)   * 512]);
    gl_lds16(Kg + (size_t)kt * 4096 + (2*w+1) * 512 + lane * 8, &Ks[(2*w+1) * 512]);
    gl_lds16(Vg + (size_t)kt * 4096 + (2*w)   * 512 + lane * 8, &Vs[(2*w)   * 512]);
    gl_lds16(Vg + (size_t)kt * 4096 + (2*w+1) * 512 + lane * 8, &Vs[(2*w+1) * 512]);
    __syncthreads();
    if (kbase > qlast) continue;          // uniform; barrier count stays aligned

    const uint64_t mb = __ballot(amask[b * S_ + kbase + lane] != 0);

    // ---- S^T = K . Q^T ----
    f32x4 sc[2][4];
#pragma unroll
    for (int mt = 0; mt < 2; ++mt)
#pragma unroll
      for (int cb = 0; cb < 4; ++cb) sc[mt][cb] = (f32x4){0.f,0.f,0.f,0.f};
#pragma unroll
    for (int cb = 0; cb < 4; ++cb) {
      const bf16x8 bk0 = *(const bf16x8*)&Ks[(cb*16 + m) * 64 + x0 * 8];
      const bf16x8 bk1 = *(const bf16x8*)&Ks[(cb*16 + m) * 64 + x1 * 8];
#pragma unroll
      for (int mt = 0; mt < 2; ++mt) {
        sc[mt][cb] = __builtin_amdgcn_mfma_f32_16x16x32_bf16(bk0, aq[mt][0], sc[mt][cb], 0, 0, 0);
        sc[mt][cb] = __builtin_amdgcn_mfma_f32_16x16x32_bf16(bk1, aq[mt][1], sc[mt][cb], 0, 0, 0);
      }
    }

    // ---- online softmax (per-lane state; lane&15 = q) ----
    f16x4 bp[2][4];
#pragma unroll
    for (int mt = 0; mt < 2; ++mt) {
      const bool fullt = (kbase + 63 <= q0w + mt*16) && (mb == ~0ull);
      if (!fullt) {
        const int qv = q0w + mt*16 + m;
#pragma unroll
        for (int cb = 0; cb < 4; ++cb)
#pragma unroll
          for (int r = 0; r < 4; ++r) {
            const int idx = cb*16 + quad*4 + r;
            const bool ok = (kbase + idx <= qv) && ((mb >> idx) & 1);
            sc[mt][cb][r] = ok ? sc[mt][cb][r] : -1e30f;
          }
      }
      float mx = -1e30f;
#pragma unroll
      for (int cb = 0; cb < 4; ++cb)
#pragma unroll
        for (int r = 0; r < 4; ++r) mx = fmaxf(mx, sc[mt][cb][r]);
      mx = fmaxf(mx, __shfl_xor(mx, 16));
      mx = fmaxf(mx, __shfl_xor(mx, 32));
      const float mn = fmaxf(m_i[mt], mx);
      const float alpha = __expf(m_i[mt] - mn);
      m_i[mt] = mn;
      float sum = 0.f;
#pragma unroll
      for (int cb = 0; cb < 4; ++cb)
#pragma unroll
        for (int r = 0; r < 4; ++r) {
          const float pv = __expf(sc[mt][cb][r] - mn);
          sc[mt][cb][r] = pv;
          sum += pv;
        }
      sum += __shfl_xor(sum, 16);
      sum += __shfl_xor(sum, 32);
      l_i[mt] = l_i[mt] * alpha + sum;
#pragma unroll
      for (int d = 0; d < 4; ++d) oacc[mt][d] *= alpha;
#pragma unroll
      for (int cb = 0; cb < 4; ++cb) {
        f16x4 pp;
        pp[0] = (f16_t)sc[mt][cb][0]; pp[1] = (f16_t)sc[mt][cb][1];
        pp[2] = (f16_t)sc[mt][cb][2]; pp[3] = (f16_t)sc[mt][cb][3];
        bp[mt][cb] = pp;
      }
    }

    // ---- O^T += V^T . P^T  (16x16x16 f16, P in registers) ----
#pragma unroll
    for (int cb = 0; cb < 4; ++cb) {
      const int off = (((2*cb + (quad >> 1)) ^ (m & 7)) * 8) + (quad & 1) * 4;
      f16x4 av[4];
#pragma unroll
      for (int dblk = 0; dblk < 4; ++dblk)
        av[dblk] = *(const f16x4*)&Vs[(dblk*16 + m) * 64 + off];
#pragma unroll
      for (int mt = 0; mt < 2; ++mt)
#pragma unroll
        for (int dblk = 0; dblk < 4; ++dblk)
          oacc[mt][dblk] = __builtin_amdgcn_mfma_f32_16x16x16f16(av[dblk], bp[mt][cb], oacc[mt][dblk], 0, 0, 0);
    }
  }

  // ---- epilogue: O[q][d] = O^T/l, b64 bf16 stores ----
#pragma unroll
  for (int mt = 0; mt < 2; ++mt) {
    const float inv = 1.0f / l_i[mt];
    const size_t row = (size_t)(b * S_ + q0w + mt*16 + m);
#pragma unroll
    for (int dblk = 0; dblk < 4; ++dblk) {
      bf16x4 o;
      o[0] = (bf16_t)(oacc[mt][dblk][0] * inv);
      o[1] = (bf16_t)(oacc[mt][dblk][1] * inv);
      o[2] = (bf16_t)(oacc[mt][dblk][2] * inv);
      o[3] = (bf16_t)(oacc[mt][dblk][3] * inv);
      *(bf16x4*)&Ab[row * HID + h * DH_ + dblk * 16 + quad * 4] = o;
    }
  }
}

// ---------------------------------------------------------------------------
extern "C" void kernel_launch(void* const* d_in, const int* in_sizes, int n_in,
                              void* d_out, int out_size, void* d_ws, size_t ws_size,
                              hipStream_t stream)
{
  const float* hs    = (const float*)d_in[0];
  const int*   amask = (const int*)  d_in[1];
  const float* Wq    = (const float*)d_in[2];
  const float* bq    = (const float*)d_in[3];
  const float* Wk    = (const float*)d_in[4];
  const float* bk    = (const float*)d_in[5];
  const float* Wv    = (const float*)d_in[6];
  const float* bv    = (const float*)d_in[7];
  const float* Wo    = (const float*)d_in[8];
  const float* bo    = (const float*)d_in[9];
  float* out = (float*)d_out;

  // workspace layout (~42.2 MB)
  float*  QKV = (float*)d_ws;                          // ROWS*1536 f32 (25.2 MB)
  bf16_t* hsb = (bf16_t*)(QKV + (size_t)ROWS * NQKV);  // ROWS*1024 bf16 (8 MB)
  bf16_t* Wt  = hsb + (size_t)ROWS * HID;              // 1536*1024 bf16 (3 MB)
  bf16_t* Wot = Wt + (size_t)NQKV * HID;               // 1024*1024 bf16 (2 MB)
  float*  ball= (float*)(Wot + (size_t)HID * HID);     // 1536 f32
  bf16_t* Kt2 = (bf16_t*)(ball + NQKV);                // 2*4*32*4096 bf16 (2 MB)
  f16_t*  Vt2 = (f16_t*)(Kt2 + (size_t)B_*NKV_*32*4096); // same count f16 (2 MB)
  bf16_t* Qb  = hsb;                                   // alias: hsb dead after QKV GEMM
  bf16_t* Ab  = (bf16_t*)QKV;                          // alias: QKV dead after prep_kv

  cast_bf16<<<(ROWS * HID / 8 + 255) / 256, 256, 0, stream>>>(hs, hsb, ROWS * HID);
  prep_w<<<2566, 256, 0, stream>>>(Wq, Wk, Wv, Wo, bq, bk, bv, Wt, Wot, ball);

  // fused QKV projection (fp32 out)
  gemm_bt_bf16<<<dim3(NQKV/128, ROWS/128), 256, 0, stream>>>(hsb, Wt, ball, QKV, ROWS, NQKV, HID);

  // RoPE + cast + (re)layout
  prep_q<<<ROWS, 256, 0, stream>>>(QKV, Qb);
  prep_kv<<<dim3(S_/64, NKV_, B_), 256, 0, stream>>>(QKV, Kt2, Vt2);

  // attention
  attn_v2<<<dim3(16, NH_, B_), 256, 0, stream>>>(Qb, Kt2, Vt2, amask, Ab);

  // output projection
  gemm_bt_bf16<<<dim3(HID/128, ROWS/128), 256, 0, stream>>>(Ab, Wot, bo, out, ROWS, HID, HID);
}